// Round 1
// baseline (1743.401 us; speedup 1.0000x reference)
//
#include <hip/hip_runtime.h>
#include <math.h>

#define B_SZ 128
#define L_SZ 2048
#define DMODEL 1024
#define NH 8
#define DK 128
#define S_CHUNKS 8
#define L_CHUNK (L_SZ / S_CHUNKS)  // 256

// ws layout (floats)
#define WS_QS    0            // 128*1024
#define WS_WEFF  131072       // 128*8*1024
#define WS_SBIAS 1179648      // 128*8
#define WS_CTX   1180672      // 128*8*1024
#define WS_TOTAL 2229248      // ~8.9 MB

// ---------------- qs = q @ Wq^T + bq  (M=128, N=1024, K=1024) ----------------
// Bt is N x K row-major (Wq as stored). Tile: 16 m x 64 n, K-step 32.
__global__ __launch_bounds__(256) void gemm_nt_kernel(
    const float* __restrict__ A, int lda,
    const float* __restrict__ Bt, int ldb,
    const float* __restrict__ bias,
    float* __restrict__ C, int ldc, int K)
{
    __shared__ float As[16][33];
    __shared__ float Bs[32 * 64];  // XOR-swizzled
    const int t = threadIdx.x;
    const int n0 = blockIdx.x * 64;
    const int m0 = blockIdx.y * 16;
    const int mm = t >> 4;           // 0..15
    const int cg = t & 15;           // n float4-group 0..15
    float acc0 = 0.f, acc1 = 0.f, acc2 = 0.f, acc3 = 0.f;
    for (int k0 = 0; k0 < K; k0 += 32) {
        __syncthreads();
#pragma unroll
        for (int i = 0; i < 2; i++) {
            int e = t + i * 256; int am = e >> 5, ak = e & 31;
            As[am][ak] = A[(m0 + am) * lda + k0 + ak];
        }
#pragma unroll
        for (int i = 0; i < 8; i++) {
            int e = t + i * 256; int bn = e >> 5, bk = e & 31;
            // swizzled store: row bk, logical col bn
            Bs[bk * 64 + ((((bn >> 2) ^ (bk & 15)) << 2) | (bn & 3))] =
                Bt[(n0 + bn) * ldb + k0 + bk];
        }
        __syncthreads();
#pragma unroll
        for (int kk = 0; kk < 32; kk++) {
            float a = As[mm][kk];
            float4 b4 = *(const float4*)&Bs[kk * 64 + ((cg ^ (kk & 15)) << 2)];
            acc0 += a * b4.x; acc1 += a * b4.y; acc2 += a * b4.z; acc3 += a * b4.w;
        }
    }
    int nn4 = cg << 2;
    float4 o;
    o.x = acc0 + (bias ? bias[n0 + nn4 + 0] : 0.f);
    o.y = acc1 + (bias ? bias[n0 + nn4 + 1] : 0.f);
    o.z = acc2 + (bias ? bias[n0 + nn4 + 2] : 0.f);
    o.w = acc3 + (bias ? bias[n0 + nn4 + 3] : 0.f);
    *(float4*)&C[(m0 + mm) * ldc + n0 + nn4] = o;
}

// ---------------- w_eff[b,h,c] = sum_d qs[b,h*128+d] * Wk[h*128+d, c] ----------------
// per h: M=128(b), N=1024(c), K=128(d); B in natural (k,n) layout.
__global__ __launch_bounds__(256) void weff_kernel(
    const float* __restrict__ qs,   // (128,1024)
    const float* __restrict__ Wk,   // (1024,1024)
    float* __restrict__ weff)       // (128,8,1024)
{
    __shared__ float As[16][33];
    __shared__ float Bs[32 * 64];
    const int t = threadIdx.x;
    const int h = blockIdx.z;
    const int n0 = blockIdx.x * 64;
    const int m0 = blockIdx.y * 16;
    const int mm = t >> 4;
    const int cg = t & 15;
    float acc0 = 0.f, acc1 = 0.f, acc2 = 0.f, acc3 = 0.f;
    for (int k0 = 0; k0 < 128; k0 += 32) {
        __syncthreads();
#pragma unroll
        for (int i = 0; i < 2; i++) {
            int e = t + i * 256; int am = e >> 5, ak = e & 31;
            As[am][ak] = qs[(m0 + am) * 1024 + h * 128 + k0 + ak];
        }
#pragma unroll
        for (int i = 0; i < 8; i++) {
            int e = t + i * 256; int bk = e >> 6, bn = e & 63;
            Bs[bk * 64 + ((((bn >> 2) ^ (bk & 15)) << 2) | (bn & 3))] =
                Wk[(h * 128 + k0 + bk) * 1024 + n0 + bn];
        }
        __syncthreads();
#pragma unroll
        for (int kk = 0; kk < 32; kk++) {
            float a = As[mm][kk];
            float4 b4 = *(const float4*)&Bs[kk * 64 + ((cg ^ (kk & 15)) << 2)];
            acc0 += a * b4.x; acc1 += a * b4.y; acc2 += a * b4.z; acc3 += a * b4.w;
        }
    }
    int nn4 = cg << 2;
    float4 o = {acc0, acc1, acc2, acc3};
    *(float4*)&weff[(m0 + mm) * (NH * 1024) + h * 1024 + n0 + nn4] = o;
}

// ---------------- sbias[b,h] = sum_d qs[b,h*128+d]*bk[h*128+d] ----------------
__global__ __launch_bounds__(256) void sbias_kernel(
    const float* __restrict__ qs, const float* __restrict__ bk,
    float* __restrict__ sbias)
{
    int idx = blockIdx.x * 256 + threadIdx.x;  // 0..1023 = b*8+h
    int b = idx >> 3, h = idx & 7;
    float s = 0.f;
    for (int d = 0; d < 128; d++)
        s += qs[b * 1024 + h * 128 + d] * bk[h * 128 + d];
    sbias[idx] = s;
}

// ---------------- scores[h*128+b, l] = (k[b,l,:]·weff[b,h,:] + sbias)/sqrt(128) ------
// block: b x 32 l-rows; wave: 8 rows x 8 lanes/row; weff staged in LDS (32KB).
__global__ __launch_bounds__(256) void scores_kernel(
    const float* __restrict__ kin,   // (128,2048,1024)
    const float* __restrict__ weff,  // (128,8,1024)
    const float* __restrict__ sbias, // (128,8)
    float* __restrict__ attn)        // (8*128,2048) raw scores
{
    __shared__ float w_lds[NH * 1024];
    const int t = threadIdx.x;
    const int b = blockIdx.y;
    const int l0 = blockIdx.x * 32;
#pragma unroll
    for (int i = 0; i < 8; i++) {
        int e4 = (t + i * 256) << 2;
        *(float4*)&w_lds[e4] = *(const float4*)&weff[b * (NH * 1024) + e4];
    }
    __syncthreads();
    const int wave = t >> 6, lane = t & 63;
    const int r = lane >> 3, g = lane & 7;
    const int l = l0 + wave * 8 + r;
    const float* krow = kin + ((size_t)b * L_SZ + l) * 1024;
    float acc[8] = {0.f, 0.f, 0.f, 0.f, 0.f, 0.f, 0.f, 0.f};
#pragma unroll 4
    for (int j = 0; j < 32; j++) {
        int c = (g << 2) + (j << 5);
        float4 k4 = *(const float4*)&krow[c];
#pragma unroll
        for (int h = 0; h < 8; h++) {
            float4 w4 = *(const float4*)&w_lds[h * 1024 + c];
            acc[h] += k4.x * w4.x + k4.y * w4.y + k4.z * w4.z + k4.w * w4.w;
        }
    }
#pragma unroll
    for (int h = 0; h < 8; h++) {
        float v = acc[h];
        v += __shfl_xor(v, 1);
        v += __shfl_xor(v, 2);
        v += __shfl_xor(v, 4);
        acc[h] = v;
    }
    if (g == 0) {
        const float inv_temp = 0.08838834764831845f;  // 1/sqrt(128)
#pragma unroll
        for (int h = 0; h < 8; h++)
            attn[((size_t)(h * 128 + b)) * L_SZ + l] =
                (acc[h] + sbias[b * 8 + h]) * inv_temp;
    }
}

// ---------------- softmax over l, in place on (8*128, 2048) ----------------
__global__ __launch_bounds__(256) void softmax_kernel(float* __restrict__ attn)
{
    float* p = attn + (size_t)blockIdx.x * L_SZ;
    const int t = threadIdx.x;
    const int lane = t & 63, wv = t >> 6;
    float4 v0 = ((float4*)p)[t];
    float4 v1 = ((float4*)p)[t + 256];
    float m = fmaxf(fmaxf(fmaxf(v0.x, v0.y), fmaxf(v0.z, v0.w)),
                    fmaxf(fmaxf(v1.x, v1.y), fmaxf(v1.z, v1.w)));
#pragma unroll
    for (int s = 32; s; s >>= 1) m = fmaxf(m, __shfl_xor(m, s));
    __shared__ float red[8];
    if (lane == 0) red[wv] = m;
    __syncthreads();
    m = fmaxf(fmaxf(red[0], red[1]), fmaxf(red[2], red[3]));
    v0.x = __expf(v0.x - m); v0.y = __expf(v0.y - m);
    v0.z = __expf(v0.z - m); v0.w = __expf(v0.w - m);
    v1.x = __expf(v1.x - m); v1.y = __expf(v1.y - m);
    v1.z = __expf(v1.z - m); v1.w = __expf(v1.w - m);
    float s = v0.x + v0.y + v0.z + v0.w + v1.x + v1.y + v1.z + v1.w;
#pragma unroll
    for (int sh = 32; sh; sh >>= 1) s += __shfl_xor(s, sh);
    if (lane == 0) red[4 + wv] = s;
    __syncthreads();
    float inv = 1.f / (red[4] + red[5] + red[6] + red[7]);
    v0.x *= inv; v0.y *= inv; v0.z *= inv; v0.w *= inv;
    v1.x *= inv; v1.y *= inv; v1.z *= inv; v1.w *= inv;
    ((float4*)p)[t] = v0;
    ((float4*)p)[t + 256] = v1;
}

// ---------------- ctx[b,h,c] += sum_{l in chunk} attn[h,b,l]*k[b,l,c] ----------------
// block: (s-chunk, b); 256 threads = lanes over c (float4); atomicAdd partials.
__global__ __launch_bounds__(256) void ctx_kernel(
    const float* __restrict__ kin,
    const float* __restrict__ attn,  // normalized (8*128,2048)
    float* __restrict__ ctx)         // (128,8,1024), pre-zeroed
{
    __shared__ float a_lds[NH * L_CHUNK];  // 8*256
    const int t = threadIdx.x;
    const int s = blockIdx.x;
    const int b = blockIdx.y;
#pragma unroll
    for (int i = 0; i < 8; i++) {
        int e = t + i * 256; int h = e >> 8, ll = e & 255;
        a_lds[e] = attn[((size_t)(h * 128 + b)) * L_SZ + s * L_CHUNK + ll];
    }
    __syncthreads();
    float4 acc[8];
#pragma unroll
    for (int h = 0; h < 8; h++) acc[h] = make_float4(0.f, 0.f, 0.f, 0.f);
    const float* kbase = kin + ((size_t)b * L_SZ + s * L_CHUNK) * 1024 + (t << 2);
    for (int l = 0; l < L_CHUNK; l++) {
        float4 k4 = *(const float4*)(kbase + (size_t)l * 1024);
#pragma unroll
        for (int h = 0; h < 8; h++) {
            float a = a_lds[h * L_CHUNK + l];
            acc[h].x += a * k4.x; acc[h].y += a * k4.y;
            acc[h].z += a * k4.z; acc[h].w += a * k4.w;
        }
    }
#pragma unroll
    for (int h = 0; h < 8; h++) {
        float* dst = &ctx[((size_t)b * 8 + h) * 1024 + (t << 2)];
        atomicAdd(dst + 0, acc[h].x);
        atomicAdd(dst + 1, acc[h].y);
        atomicAdd(dst + 2, acc[h].z);
        atomicAdd(dst + 3, acc[h].w);
    }
}

// ---------------- out[b, h*128+d] = ctx[b,h,:]·Wv[h*128+d,:] + bv ----------------
__global__ __launch_bounds__(256) void outproj_kernel(
    const float* __restrict__ ctx,  // (128,8,1024)
    const float* __restrict__ Wv,   // (1024,1024)
    const float* __restrict__ bv,
    float* __restrict__ out)        // (128,1024)
{
    __shared__ float As[16][33];
    __shared__ float Bs[32 * 64];
    const int t = threadIdx.x;
    const int n0 = blockIdx.x * 64;
    const int h = n0 >> 7;
    const int m0 = blockIdx.y * 16;
    const int mm = t >> 4;
    const int cg = t & 15;
    float acc0 = 0.f, acc1 = 0.f, acc2 = 0.f, acc3 = 0.f;
    for (int k0 = 0; k0 < 1024; k0 += 32) {
        __syncthreads();
#pragma unroll
        for (int i = 0; i < 2; i++) {
            int e = t + i * 256; int am = e >> 5, ak = e & 31;
            As[am][ak] = ctx[(m0 + am) * (NH * 1024) + h * 1024 + k0 + ak];
        }
#pragma unroll
        for (int i = 0; i < 8; i++) {
            int e = t + i * 256; int bn = e >> 5, bk = e & 31;
            Bs[bk * 64 + ((((bn >> 2) ^ (bk & 15)) << 2) | (bn & 3))] =
                Wv[(n0 + bn) * 1024 + k0 + bk];
        }
        __syncthreads();
#pragma unroll
        for (int kk = 0; kk < 32; kk++) {
            float a = As[mm][kk];
            float4 b4 = *(const float4*)&Bs[kk * 64 + ((cg ^ (kk & 15)) << 2)];
            acc0 += a * b4.x; acc1 += a * b4.y; acc2 += a * b4.z; acc3 += a * b4.w;
        }
    }
    int nn4 = cg << 2;
    float4 o;
    o.x = acc0 + bv[n0 + nn4 + 0];
    o.y = acc1 + bv[n0 + nn4 + 1];
    o.z = acc2 + bv[n0 + nn4 + 2];
    o.w = acc3 + bv[n0 + nn4 + 3];
    *(float4*)&out[(m0 + mm) * 1024 + n0 + nn4] = o;
}

extern "C" void kernel_launch(void* const* d_in, const int* in_sizes, int n_in,
                              void* d_out, int out_size, void* d_ws, size_t ws_size,
                              hipStream_t stream) {
    const float* q  = (const float*)d_in[0];
    const float* k  = (const float*)d_in[1];
    const float* Wq = (const float*)d_in[2];
    const float* bq = (const float*)d_in[3];
    const float* Wk = (const float*)d_in[4];
    const float* bk = (const float*)d_in[5];
    const float* Wv = (const float*)d_in[6];
    const float* bv = (const float*)d_in[7];

    float* ws    = (float*)d_ws;
    float* qs    = ws + WS_QS;
    float* weff  = ws + WS_WEFF;
    float* sbias = ws + WS_SBIAS;
    float* ctx   = ws + WS_CTX;

    float* out  = (float*)d_out;                 // (128, 1024)
    float* attn = (float*)d_out + 128 * 1024;    // (8*128, 2048)

    // 1. qs = q @ Wq^T + bq
    gemm_nt_kernel<<<dim3(16, 8), 256, 0, stream>>>(q, 1024, Wq, 1024, bq, qs, 1024, 1024);
    // 2. w_eff
    weff_kernel<<<dim3(16, 8, 8), 256, 0, stream>>>(qs, Wk, weff);
    // 3. sbias
    sbias_kernel<<<4, 256, 0, stream>>>(qs, bk, sbias);
    // 4. raw scores into attn slot
    scores_kernel<<<dim3(64, 128), 256, 0, stream>>>(k, weff, sbias, attn);
    // 5. softmax in place
    softmax_kernel<<<1024, 256, 0, stream>>>(attn);
    // 6. zero ctx, then accumulate
    hipMemsetAsync(ctx, 0, (size_t)128 * 8 * 1024 * sizeof(float), stream);
    ctx_kernel<<<dim3(S_CHUNKS, 128), 256, 0, stream>>>(k, attn, ctx);
    // 7. output projection
    outproj_kernel<<<dim3(16, 8), 256, 0, stream>>>(ctx, Wv, bv, out);
}